// Round 1
// baseline (257.881 us; speedup 1.0000x reference)
//
#include <hip/hip_runtime.h>
#include <hip/hip_bf16.h>

typedef __attribute__((ext_vector_type(4))) float f32x4;
typedef __attribute__((ext_vector_type(8))) short s16x8;
typedef __attribute__((ext_vector_type(4))) short s16x4;

#define LXS 264   // lx / l_attn row stride (bf16 elems)  (256 + 8 pad)
#define LQS 520   // lqk row stride (512 + 8 pad)
#define LVS 72    // lvT row stride over j (64 + 8 pad)

// smem layout (bytes)
#define OFF_LQK   0
#define SZ_LQK    (64 * LQS * 2)          // 66560
#define OFF_LVT   (OFF_LQK + SZ_LQK)
#define SZ_LVT    (8 * 32 * LVS * 2)      // 36864
#define OFF_LX    (OFF_LVT + SZ_LVT)
#define SZ_LX     (64 * LXS * 2)          // 33792
#define OFF_LB    (OFF_LX + SZ_LX)
#define SZ_LB     (169 * 8 * 4)           // 5408
#define SMEM_BYTES (OFF_LB + SZ_LB)       // 142624

__device__ __forceinline__ short f2bf(float f) {
    unsigned u = __builtin_bit_cast(unsigned, f);
    unsigned r = (u + 0x7FFFu + ((u >> 16) & 1u)) >> 16;
    return (short)r;
}

__device__ __forceinline__ int region_id(int wy, int wx, int ty, int tx) {
    int rr = wy * 7 + ty;
    int cc = wx * 7 + tx;
    int rh = (rr < 49) ? 0 : ((rr < 53) ? 1 : 2);
    int rw = (cc < 49) ? 0 : ((cc < 53) ? 1 : 2);
    return rh * 3 + rw;
}

// K0: convert weights fp32 -> bf16 into workspace
__global__ void wcvt_kernel(const float* __restrict__ qw, const float* __restrict__ pw,
                            short* __restrict__ wqkv, short* __restrict__ wproj) {
    int idx = blockIdx.x * blockDim.x + threadIdx.x;
    int stride = gridDim.x * blockDim.x;
    // 768*256 = 196608 (=49152 vec4) qkv + 256*256 = 65536 (=16384 vec4) proj
    for (int i = idx; i < 65536; i += stride) {
        if (i < 49152) {
            const f32x4 v = *(const f32x4*)(qw + i * 4);
            s16x4 o = { f2bf(v.x), f2bf(v.y), f2bf(v.z), f2bf(v.w) };
            *(s16x4*)(wqkv + i * 4) = o;
        } else {
            int j = i - 49152;
            const f32x4 v = *(const f32x4*)(pw + j * 4);
            s16x4 o = { f2bf(v.x), f2bf(v.y), f2bf(v.z), f2bf(v.w) };
            *(s16x4*)(wproj + j * 4) = o;
        }
    }
}

__global__ __launch_bounds__(512, 2)
void swin_kernel(const float* __restrict__ x,
                 const float* __restrict__ qkv_bias,
                 const float* __restrict__ proj_bias,
                 const float* __restrict__ rpb,
                 const short* __restrict__ wqkv,
                 const short* __restrict__ wproj,
                 float* __restrict__ out) {
    __shared__ __align__(16) char smem[SMEM_BYTES];
    short* lqk   = (short*)(smem + OFF_LQK);
    short* lvT   = (short*)(smem + OFF_LVT);
    short* lx    = (short*)(smem + OFF_LX);   // reused as l_attn after qkv phase
    float* lbias = (float*)(smem + OFF_LB);

    const int tid  = threadIdx.x;
    const int w    = tid >> 6;        // wave id == head id
    const int lane = tid & 63;
    const int il   = lane & 15;
    const int gl   = lane >> 4;

    const int b   = blockIdx.x >> 6;
    const int wid = blockIdx.x & 63;
    const int wy  = wid >> 3, wx = wid & 7;

    // ---------------- stage rpb table + window input ----------------
    for (int i = tid; i < 1352; i += 512) lbias[i] = rpb[i];
    for (int i = tid; i < 4096; i += 512) {  // 64 rows x 64 float4 chunks
        int t = i >> 6, c4 = (i & 63) << 2;
        s16x4 o;
        if (t < 49) {
            int ty = t / 7, tx = t % 7;
            int R = wy * 7 + ty + 3; if (R >= 56) R -= 56;
            int C = wx * 7 + tx + 3; if (C >= 56) C -= 56;
            const f32x4 v = *(const f32x4*)(x + (((b * 56 + R) * 56 + C) << 8) + c4);
            o = (s16x4){ f2bf(v.x), f2bf(v.y), f2bf(v.z), f2bf(v.w) };
        } else {
            o = (s16x4){ 0, 0, 0, 0 };
        }
        *(s16x4*)&lx[t * LXS + c4] = o;
    }
    __syncthreads();

    // ---------------- QKV GEMM: wave w computes head-w columns ----------------
    {
        int cb[6];
        cb[0] = 32 * w;       cb[1] = 32 * w + 16;
        cb[2] = 256 + 32 * w; cb[3] = 256 + 32 * w + 16;
        cb[4] = 512 + 32 * w; cb[5] = 512 + 32 * w + 16;
        f32x4 acc[4][6];
        #pragma unroll
        for (int mi = 0; mi < 4; mi++)
            #pragma unroll
            for (int ni = 0; ni < 6; ni++) acc[mi][ni] = (f32x4){0.f, 0.f, 0.f, 0.f};

        for (int k0 = 0; k0 < 256; k0 += 32) {
            s16x8 a[4], bf[6];
            #pragma unroll
            for (int mi = 0; mi < 4; mi++)
                a[mi] = *(const s16x8*)&lx[(mi * 16 + il) * LXS + k0 + 8 * gl];
            #pragma unroll
            for (int ni = 0; ni < 6; ni++)
                bf[ni] = *(const s16x8*)(wqkv + (cb[ni] + il) * 256 + k0 + 8 * gl);
            #pragma unroll
            for (int ni = 0; ni < 6; ni++)
                #pragma unroll
                for (int mi = 0; mi < 4; mi++)
                    acc[mi][ni] = __builtin_amdgcn_mfma_f32_16x16x32_bf16(a[mi], bf[ni], acc[mi][ni], 0, 0, 0);
        }
        // write q,k (scaled q) to lqk; v transposed to lvT
        #pragma unroll
        for (int ni = 0; ni < 6; ni++) {
            int col = cb[ni] + il;
            float bv = qkv_bias[col];
            if (ni < 4) {
                float scl = (ni < 2) ? 0.17677669529663687f : 1.0f;
                #pragma unroll
                for (int mi = 0; mi < 4; mi++)
                    #pragma unroll
                    for (int r = 0; r < 4; r++)
                        lqk[(mi * 16 + gl * 4 + r) * LQS + col] = f2bf((acc[mi][ni][r] + bv) * scl);
            } else {
                int d = (ni - 4) * 16 + il;
                #pragma unroll
                for (int mi = 0; mi < 4; mi++) {
                    s16x4 pk = { f2bf(acc[mi][ni][0] + bv), f2bf(acc[mi][ni][1] + bv),
                                 f2bf(acc[mi][ni][2] + bv), f2bf(acc[mi][ni][3] + bv) };
                    *(s16x4*)&lvT[(w * 32 + d) * LVS + mi * 16 + gl * 4] = pk;
                }
            }
        }
    }
    __syncthreads();   // all lx reads done (lx will be overwritten as l_attn)

    // ---------------- attention, head h = w ----------------
    const int h = w;
    f32x4 s[4][4];
    {
        s16x8 ak[4], bq[4];
        #pragma unroll
        for (int mi = 0; mi < 4; mi++)
            ak[mi] = *(const s16x8*)&lqk[(mi * 16 + il) * LQS + 256 + 32 * h + 8 * gl];
        #pragma unroll
        for (int ni = 0; ni < 4; ni++)
            bq[ni] = *(const s16x8*)&lqk[(ni * 16 + il) * LQS + 32 * h + 8 * gl];
        #pragma unroll
        for (int mi = 0; mi < 4; mi++)
            #pragma unroll
            for (int ni = 0; ni < 4; ni++)
                s[mi][ni] = __builtin_amdgcn_mfma_f32_16x16x32_bf16(ak[mi], bq[ni], (f32x4){0.f,0.f,0.f,0.f}, 0, 0, 0);
    }
    // scores layout: s[mi][ni][r] = score[ query i = ni*16+il ][ key j = mi*16+gl*4+r ]
    int yi[4], xi[4], cnti[4];
    #pragma unroll
    for (int ni = 0; ni < 4; ni++) {
        int i = ni * 16 + il; int ic = i > 48 ? 48 : i;
        yi[ni] = ic / 7; xi[ni] = ic % 7;
        cnti[ni] = region_id(wy, wx, yi[ni], xi[ni]);
    }
    float mx[4] = { -1e30f, -1e30f, -1e30f, -1e30f };
    #pragma unroll
    for (int mi = 0; mi < 4; mi++) {
        #pragma unroll
        for (int r = 0; r < 4; r++) {
            int j = mi * 16 + gl * 4 + r;
            bool jok = (j < 49);
            int jc = jok ? j : 48;
            int yj = jc / 7, xj = jc % 7;
            int cj = region_id(wy, wx, yj, xj);
            #pragma unroll
            for (int ni = 0; ni < 4; ni++) {
                float v;
                if (jok) {
                    float bb = lbias[((yi[ni] - yj + 6) * 13 + (xi[ni] - xj + 6)) * 8 + h];
                    v = s[mi][ni][r] + bb + ((cnti[ni] != cj) ? -100.0f : 0.0f);
                } else {
                    v = -1e30f;
                }
                s[mi][ni][r] = v;
                mx[ni] = fmaxf(mx[ni], v);
            }
        }
    }
    #pragma unroll
    for (int ni = 0; ni < 4; ni++) {
        mx[ni] = fmaxf(mx[ni], __shfl_xor(mx[ni], 16));
        mx[ni] = fmaxf(mx[ni], __shfl_xor(mx[ni], 32));
    }
    float sum[4] = { 0.f, 0.f, 0.f, 0.f };
    #pragma unroll
    for (int mi = 0; mi < 4; mi++)
        #pragma unroll
        for (int ni = 0; ni < 4; ni++)
            #pragma unroll
            for (int r = 0; r < 4; r++) {
                float p = __expf(s[mi][ni][r] - mx[ni]);
                s[mi][ni][r] = p;
                sum[ni] += p;
            }
    #pragma unroll
    for (int ni = 0; ni < 4; ni++) {
        sum[ni] += __shfl_xor(sum[ni], 16);
        sum[ni] += __shfl_xor(sum[ni], 32);
        sum[ni] = 1.0f / sum[ni];
    }
    // pack P rows (pairs along j) to bf16
    unsigned pkd[4][4][2];
    #pragma unroll
    for (int mi = 0; mi < 4; mi++)
        #pragma unroll
        for (int ni = 0; ni < 4; ni++) {
            float p0 = s[mi][ni][0] * sum[ni], p1 = s[mi][ni][1] * sum[ni];
            float p2 = s[mi][ni][2] * sum[ni], p3 = s[mi][ni][3] * sum[ni];
            pkd[mi][ni][0] = (unsigned)(unsigned short)f2bf(p0) | ((unsigned)(unsigned short)f2bf(p1) << 16);
            pkd[mi][ni][1] = (unsigned)(unsigned short)f2bf(p2) | ((unsigned)(unsigned short)f2bf(p3) << 16);
        }
    // PV: outT[d][i] = sum_j vT[d][j] * P[j][i]
    f32x4 o[2][4];
    #pragma unroll
    for (int md = 0; md < 2; md++)
        #pragma unroll
        for (int ni = 0; ni < 4; ni++) o[md][ni] = (f32x4){0.f, 0.f, 0.f, 0.f};
    #pragma unroll
    for (int ks = 0; ks < 2; ks++) {
        s16x8 bp[4];
        #pragma unroll
        for (int ni = 0; ni < 4; ni++) {
            unsigned wd[4];
            #pragma unroll
            for (int q = 0; q < 4; q++) {
                int src = (2 * (gl & 1) + (q >> 1)) * 16 + il;
                unsigned v0 = (unsigned)__shfl((int)pkd[2 * ks    ][ni][q & 1], src);
                unsigned v1 = (unsigned)__shfl((int)pkd[2 * ks + 1][ni][q & 1], src);
                wd[q] = (gl & 2) ? v1 : v0;
            }
            union { unsigned u[4]; s16x8 v; } cv;
            cv.u[0] = wd[0]; cv.u[1] = wd[1]; cv.u[2] = wd[2]; cv.u[3] = wd[3];
            bp[ni] = cv.v;
        }
        s16x8 av[2];
        #pragma unroll
        for (int md = 0; md < 2; md++)
            av[md] = *(const s16x8*)&lvT[(h * 32 + md * 16 + il) * LVS + ks * 32 + 8 * gl];
        #pragma unroll
        for (int md = 0; md < 2; md++)
            #pragma unroll
            for (int ni = 0; ni < 4; ni++)
                o[md][ni] = __builtin_amdgcn_mfma_f32_16x16x32_bf16(av[md], bp[ni], o[md][ni], 0, 0, 0);
    }
    // write attention output rows into l_attn (lx reuse): [t][c=h*32+d]
    #pragma unroll
    for (int md = 0; md < 2; md++)
        #pragma unroll
        for (int ni = 0; ni < 4; ni++) {
            s16x4 pk = { f2bf(o[md][ni][0]), f2bf(o[md][ni][1]), f2bf(o[md][ni][2]), f2bf(o[md][ni][3]) };
            *(s16x4*)&lx[(ni * 16 + il) * LXS + h * 32 + md * 16 + gl * 4] = pk;
        }
    __syncthreads();

    // ---------------- proj GEMM + scatter (reverse roll) ----------------
    {
        f32x4 acc[4][2];
        #pragma unroll
        for (int mi = 0; mi < 4; mi++)
            #pragma unroll
            for (int ni = 0; ni < 2; ni++) acc[mi][ni] = (f32x4){0.f, 0.f, 0.f, 0.f};
        for (int k0 = 0; k0 < 256; k0 += 32) {
            s16x8 a[4], bw[2];
            #pragma unroll
            for (int mi = 0; mi < 4; mi++)
                a[mi] = *(const s16x8*)&lx[(mi * 16 + il) * LXS + k0 + 8 * gl];
            #pragma unroll
            for (int ni = 0; ni < 2; ni++)
                bw[ni] = *(const s16x8*)(wproj + (32 * w + 16 * ni + il) * 256 + k0 + 8 * gl);
            #pragma unroll
            for (int mi = 0; mi < 4; mi++)
                #pragma unroll
                for (int ni = 0; ni < 2; ni++)
                    acc[mi][ni] = __builtin_amdgcn_mfma_f32_16x16x32_bf16(a[mi], bw[ni], acc[mi][ni], 0, 0, 0);
        }
        #pragma unroll
        for (int ni = 0; ni < 2; ni++) {
            int oc = 32 * w + 16 * ni + il;
            float pb = proj_bias[oc];
            #pragma unroll
            for (int mi = 0; mi < 4; mi++)
                #pragma unroll
                for (int r = 0; r < 4; r++) {
                    int t = mi * 16 + gl * 4 + r;
                    if (t < 49) {
                        int ty = t / 7, tx = t % 7;
                        int R = wy * 7 + ty + 3; if (R >= 56) R -= 56;
                        int C = wx * 7 + tx + 3; if (C >= 56) C -= 56;
                        out[(((b * 56 + R) * 56 + C) << 8) + oc] = acc[mi][ni][r] + pb;
                    }
                }
        }
    }
}

extern "C" void kernel_launch(void* const* d_in, const int* in_sizes, int n_in,
                              void* d_out, int out_size, void* d_ws, size_t ws_size,
                              hipStream_t stream) {
    const float* x   = (const float*)d_in[0];
    const float* qw  = (const float*)d_in[1];
    const float* qb  = (const float*)d_in[2];
    const float* pw  = (const float*)d_in[3];
    const float* pb  = (const float*)d_in[4];
    const float* rpb = (const float*)d_in[5];

    short* wqkv  = (short*)d_ws;            // 768*256 bf16
    short* wproj = wqkv + 768 * 256;        // 256*256 bf16

    wcvt_kernel<<<128, 256, 0, stream>>>(qw, pw, wqkv, wproj);
    swin_kernel<<<2048, 512, 0, stream>>>(x, qb, pb, rpb, wqkv, wproj, (float*)d_out);
}